// Round 5
// baseline (288.031 us; speedup 1.0000x reference)
//
#include <hip/hip_runtime.h>
#include <math.h>

typedef __bf16 bf16;
typedef __bf16 bf16x8 __attribute__((ext_vector_type(8)));
typedef float f32x4 __attribute__((ext_vector_type(4)));
typedef float f32x16 __attribute__((ext_vector_type(16)));

#define MFMA16(a, b, c) __builtin_amdgcn_mfma_f32_16x16x32_bf16((a), (b), (c), 0, 0, 0)
#define MFMA32(a, b, c) __builtin_amdgcn_mfma_f32_32x32x16_bf16((a), (b), (c), 0, 0, 0)

// NaN-laundering clamp (IEEE min/max drop NaN); inert on good data.
__device__ __forceinline__ float clampf(float v, float lo, float hi) {
  return fminf(fmaxf(v, lo), hi);
}

// Async global->LDS DMA, 16B per lane; lane i's 16B lands at base + i*16.
__device__ __forceinline__ void async_copy16(const void* g, void* l) {
  __builtin_amdgcn_global_load_lds(
      (__attribute__((address_space(1))) void*)g,
      (__attribute__((address_space(3))) void*)l,
      16, 0, 0);
}

// v_cvt_pk_bf16_f32: dword = {lo: bf16(a), hi: bf16(b)}
__device__ __forceinline__ unsigned cvtpk(float a, float b) {
  unsigned r;
  asm("v_cvt_pk_bf16_f32 %0, %1, %2" : "=v"(r) : "v"(a), "v"(b));
  return r;
}

// permlane32_swap: (a,b) -> (concat(a.lo32, b.lo32), concat(a.hi32, b.hi32))
__device__ __forceinline__ void pl32swap(unsigned& a, unsigned& b, int hi) {
#if __has_builtin(__builtin_amdgcn_permlane32_swap)
  auto r = __builtin_amdgcn_permlane32_swap(a, b, false, false);
  a = r[0];
  b = r[1];
#else
  unsigned ax = (unsigned)__shfl_xor((int)a, 32, 64);
  unsigned bx = (unsigned)__shfl_xor((int)b, 32, 64);
  unsigned o0 = hi ? bx : a;
  unsigned o1 = hi ? b : ax;
  a = o0; b = o1;
#endif
}

__device__ __forceinline__ bf16x8 frag4(unsigned d0, unsigned d1, unsigned d2, unsigned d3) {
  union { unsigned u[4]; bf16x8 v; } t;
  t.u[0] = d0; t.u[1] = d1; t.u[2] = d2; t.u[3] = d3;
  return t.v;
}

// ---------------------------------------------------------------------------
// B=2, S=2048, D_MODEL=2048, H=16, HEAD=128.  R4 post-mortem: flash sits at
// its LDS-traffic floor (34 ds_read + 16 ds_write per 16qx64kv; all counters
// <25%).  R5: m214-style 32x32 structure — swapped QK^T (mfma(K,Q)) so each
// lane owns ONE q-row; P redistributed in-register via cvt_pk_bf16 +
// permlane32_swap (NO P LDS round-trip); row-sum is a per-lane scalar.
// LDS ops per unit work halve.  2-wave blocks (64-row tiles), pair (y,31-y)
// -> uniform 33 kv-iters, grid (32,16)=512, 64KB LDS -> 2 blocks/CU.
// ---------------------------------------------------------------------------

// Elementwise fp32->bf16, 8 elems/thread.  Region boundaries in vec8 units:
// hs 1048576 | w_q 524288 | w_kv 65536 | w_proj 524288  (total 2162688).
__global__ void convert_bf16(const float* __restrict__ hs,
                             const float* __restrict__ wq,
                             const float* __restrict__ wkv,
                             const float* __restrict__ wproj,
                             bf16* __restrict__ hs_bf,
                             bf16* __restrict__ wqkv_bf,
                             bf16* __restrict__ wproj_bf) {
  const long long v = (long long)blockIdx.x * blockDim.x + threadIdx.x;
  const float* src;
  bf16* dst;
  long long off;
  if (v < 1048576) { src = hs; dst = hs_bf; off = v; }
  else if (v < 1572864) { src = wq; dst = wqkv_bf; off = v - 1048576; }
  else if (v < 1638400) { src = wkv; dst = wqkv_bf + 4194304; off = v - 1572864; }
  else { src = wproj; dst = wproj_bf; off = v - 1638400; }
  const f32x4* p = (const f32x4*)(src + off * 8);
  f32x4 f0 = p[0], f1 = p[1];
  bf16x8 r;
#pragma unroll
  for (int i = 0; i < 4; ++i) { r[i] = (bf16)f0[i]; r[i + 4] = (bf16)f1[i]; }
  *(bf16x8*)(dst + off * 8) = r;
}

// GEMM1 (m97-style): Qbuf = hs_bf @ wqkv^T cols 0..2047 (bx<16),
// Ckv = cols 2048..2303 (bx 16..17).  128x128 tile, BK=32, DMA staging.
// Bijective XCD-chunk swizzle on the linearized grid (576 = 72*8).
__global__ __launch_bounds__(256, 2)
void gemm_qkv(const bf16* __restrict__ A, const bf16* __restrict__ Bw,
              bf16* __restrict__ Cq, bf16* __restrict__ Ckv) {
  const int K = 2048;
  __shared__ bf16 As[128 * 32];
  __shared__ bf16 Bs[128 * 32];
  const int tid = threadIdx.x;
  const int wave = tid >> 6, lane = tid & 63;
  const int quad = lane >> 4, l15 = lane & 15;
  const int r4 = lane >> 2, c4 = lane & 3;
  const int wm = wave >> 1, wn = wave & 1;
  const int orig = blockIdx.x + 18 * blockIdx.y;
  const int wgid = (orig & 7) * 72 + (orig >> 3);
  const int bx = wgid % 18;
  const int bm = (wgid / 18) * 128;
  const bf16* Bp = Bw + (size_t)bx * 128 * K;

  const f32x4 vzero = {0.f, 0.f, 0.f, 0.f};
  f32x4 acc[4][4];
#pragma unroll
  for (int i = 0; i < 4; ++i)
#pragma unroll
    for (int j = 0; j < 4; ++j) acc[i][j] = vzero;

  for (int kt = 0; kt < K; kt += 32) {
    __syncthreads();
#pragma unroll
    for (int q = 0; q < 2; ++q) {
      const int chunk = wave * 2 + q;
      const int row = chunk * 16 + r4;
      async_copy16(A + (size_t)(bm + row) * K + kt + c4 * 8, (char*)As + chunk * 1024);
      async_copy16(Bp + (size_t)row * K + kt + c4 * 8, (char*)Bs + chunk * 1024);
    }
    __syncthreads();
    bf16x8 af[4], bfr[4];
#pragma unroll
    for (int i = 0; i < 4; ++i)
      af[i] = *(const bf16x8*)((const char*)As + (wm * 64 + i * 16 + l15) * 64 + quad * 16);
#pragma unroll
    for (int i = 0; i < 4; ++i)
      bfr[i] = *(const bf16x8*)((const char*)Bs + (wn * 64 + i * 16 + l15) * 64 + quad * 16);
#pragma unroll
    for (int mi = 0; mi < 4; ++mi)
#pragma unroll
      for (int ni = 0; ni < 4; ++ni)
        acc[mi][ni] = MFMA16(af[mi], bfr[ni], acc[mi][ni]);
  }

  bf16* Cp;
  int ldc, cn;
  if (bx < 16) { Cp = Cq; ldc = 2048; cn = bx * 128; }
  else { Cp = Ckv; ldc = 256; cn = (bx - 16) * 128; }
#pragma unroll
  for (int mi = 0; mi < 4; ++mi)
#pragma unroll
    for (int ni = 0; ni < 4; ++ni) {
      const int col = cn + wn * 64 + ni * 16 + l15;
#pragma unroll
      for (int r = 0; r < 4; ++r) {
        const int row = bm + wm * 64 + mi * 16 + quad * 4 + r;
        Cp[(size_t)row * ldc + col] = (bf16)clampf(acc[mi][ni][r], -1000.f, 1000.f);
      }
    }
}

// GEMM2 (m97-style): d_out(FP32) = AO(bf16) @ wproj_bf^T + b_proj(fp32).
// Bijective XCD-chunk swizzle (512 = 64*8).
__global__ __launch_bounds__(256, 2)
void gemm_proj(const bf16* __restrict__ A, const bf16* __restrict__ Bw,
               const float* __restrict__ bias, float* __restrict__ C) {
  const int K = 2048;
  __shared__ bf16 As[128 * 32];
  __shared__ bf16 Bs[128 * 32];
  const int tid = threadIdx.x;
  const int wave = tid >> 6, lane = tid & 63;
  const int quad = lane >> 4, l15 = lane & 15;
  const int r4 = lane >> 2, c4 = lane & 3;
  const int wm = wave >> 1, wn = wave & 1;
  const int orig = blockIdx.x + 16 * blockIdx.y;
  const int wgid = (orig & 7) * 64 + (orig >> 3);
  const int bn = (wgid % 16) * 128;
  const int bm = (wgid / 16) * 128;
  const bf16* Bp = Bw + (size_t)bn * K;

  const f32x4 vzero = {0.f, 0.f, 0.f, 0.f};
  f32x4 acc[4][4];
#pragma unroll
  for (int i = 0; i < 4; ++i)
#pragma unroll
    for (int j = 0; j < 4; ++j) acc[i][j] = vzero;

  for (int kt = 0; kt < K; kt += 32) {
    __syncthreads();
#pragma unroll
    for (int q = 0; q < 2; ++q) {
      const int chunk = wave * 2 + q;
      const int row = chunk * 16 + r4;
      async_copy16(A + (size_t)(bm + row) * K + kt + c4 * 8, (char*)As + chunk * 1024);
      async_copy16(Bp + (size_t)row * K + kt + c4 * 8, (char*)Bs + chunk * 1024);
    }
    __syncthreads();
    bf16x8 af[4], bfr[4];
#pragma unroll
    for (int i = 0; i < 4; ++i)
      af[i] = *(const bf16x8*)((const char*)As + (wm * 64 + i * 16 + l15) * 64 + quad * 16);
#pragma unroll
    for (int i = 0; i < 4; ++i)
      bfr[i] = *(const bf16x8*)((const char*)Bs + (wn * 64 + i * 16 + l15) * 64 + quad * 16);
#pragma unroll
    for (int mi = 0; mi < 4; ++mi)
#pragma unroll
      for (int ni = 0; ni < 4; ++ni)
        acc[mi][ni] = MFMA16(af[mi], bfr[ni], acc[mi][ni]);
  }

#pragma unroll
  for (int mi = 0; mi < 4; ++mi)
#pragma unroll
    for (int ni = 0; ni < 4; ++ni) {
      const int col = bn + wn * 64 + ni * 16 + l15;
      const float bv = bias[col];
#pragma unroll
      for (int r = 0; r < 4; ++r) {
        const int row = bm + wm * 64 + mi * 16 + quad * 4 + r;
        C[(size_t)row * 2048 + col] = clampf(acc[mi][ni][r] + bv, -1000.f, 1000.f);
      }
    }
}

// Rotary xpos + head-dim scale. Q in place in Qbuf(bf16) [row, h*128+d].
// K in place in Ckv cols 0..127. V (Ckv cols 128..255) -> VT [b,d,s].
__global__ void rotary_kernel(bf16* __restrict__ Cq, bf16* __restrict__ Ckv,
                              bf16* __restrict__ VT) {
  const int row = blockIdx.x;            // b*2048 + s
  const int b = row >> 11, s = row & 2047;
  const int t = threadIdx.x;
  const float power = (float)(s - 1024) * (1.0f / 512.0f);
  const float scale_w = 0.08838834764831845f;  // 128^-0.5
  const float k_if = 0.2076205059304679f;      // log2(10000)/64

  const int h = t >> 4;
  const int j0 = (t & 15) * 4;
  const size_t qbase = (size_t)row * 2048 + (size_t)h * 128;
#pragma unroll
  for (int u = 0; u < 4; ++u) {
    const int j = j0 + u;
    const float pos = (float)s * exp2f(-k_if * (float)j);
    const float c = cosf(pos), sn = sinf(pos);
    const float sb = ((float)(2 * j) + 51.2f) * (1.0f / 179.2f);
    const float xs = exp2f(power * log2f(sb));
    const float f = xs * scale_w;
    const float q1 = (float)Cq[qbase + j];
    const float q2 = (float)Cq[qbase + j + 64];
    Cq[qbase + j]      = (bf16)((q1 * c - q2 * sn) * f);
    Cq[qbase + j + 64] = (bf16)((q2 * c + q1 * sn) * f);
  }

  if (t < 64) {  // K in place, xpos scale inverted
    const int j = t;
    const float pos = (float)s * exp2f(-k_if * (float)j);
    const float c = cosf(pos), sn = sinf(pos);
    const float sb = ((float)(2 * j) + 51.2f) * (1.0f / 179.2f);
    const float xs = exp2f(power * log2f(sb));
    const float f = scale_w / xs;
    const size_t kvb = (size_t)row * 256;
    const float k1 = (float)Ckv[kvb + j];
    const float k2 = (float)Ckv[kvb + j + 64];
    Ckv[kvb + j]      = (bf16)((k1 * c - k2 * sn) * f);
    Ckv[kvb + j + 64] = (bf16)((k2 * c + k1 * sn) * f);
  } else if (t < 128) {  // V -> VT [b,d,s]
    const int d = (t - 64) * 2;
    const size_t kvb = (size_t)row * 256 + 128;
    VT[((size_t)b * 128 + d) * 2048 + s]     = Ckv[kvb + d];
    VT[((size_t)b * 128 + d + 1) * 2048 + s] = Ckv[kvb + d + 1];
  }
}

// Causal flash attention, MQA.  grid = (32 bh, 16 pairs); 128 threads =
// 2 waves x 32 q-rows (64-row tiles).  Block owns pair (y, 31-y)
// sequentially: uniform 33 kv-iters.  32x32x16 MFMA, swapped QK^T
// (mfma(K,Q)): lane owns q-row = q0+wrow+(lane&31); S^T lane layout
// [kv=(r&3)+8(r>>2)+4hi+32mt][q=l&31].  P -> A-frags via cvt_pk +
// permlane32_swap (no LDS).  Row-sum l is a per-lane scalar.
// Ks [kv][128d] slot^=(kv&15); Vs [d][64kv] slot^=(d&7) (both-sides swz).
__global__ __launch_bounds__(128, 1)
void flash_attn(const bf16* __restrict__ Qp, const bf16* __restrict__ Kkv,
                const bf16* __restrict__ VT, bf16* __restrict__ O) {
  __shared__ bf16 Ks[2][64 * 128];   // 32 KB: [buf][kv][d], 256B rows, 16 slots
  __shared__ bf16 Vs[2][128 * 64];   // 32 KB: [buf][d][kv], 128B rows, 8 slots

  const int tid = threadIdx.x;
  const int wave = tid >> 6, lane = tid & 63;
  const int hi = lane >> 5, l31 = lane & 31, l15 = lane & 15, l7 = lane & 7;
  const int bh = blockIdx.x, b = bh >> 4, h = bh & 15;
  const int y = blockIdx.y;              // pair index 0..15 (64-row tiles)
  const int nkvA = y + 1;                // kv-iters of light tile
  const int wrow = wave * 32;

  const bf16* Kb = Kkv + (size_t)b * 2048 * 256;
  const bf16* Vb = VT + (size_t)b * 128 * 2048;

  f32x16 sacc[2];
  f32x16 oacc[4];
  bf16x8 qb[8];
  float lacc;
  const f32x16 vz16 = {0.f, 0.f, 0.f, 0.f, 0.f, 0.f, 0.f, 0.f,
                       0.f, 0.f, 0.f, 0.f, 0.f, 0.f, 0.f, 0.f};

  // Q B-fragments: B[n=q=l31][k=d_local=8hi+j], d = 16ks+8hi+j
  auto load_q = [&](int q0) {
#pragma unroll
    for (int ks = 0; ks < 8; ++ks)
      qb[ks] = *(const bf16x8*)(Qp + ((size_t)(b * 2048 + q0 + wrow + l31)) * 2048 +
                                h * 128 + ks * 16 + hi * 8);
  };
  auto reset_acc = [&]() {
    lacc = 0.f;
#pragma unroll
    for (int nt = 0; nt < 4; ++nt) oacc[nt] = vz16;
  };

  // stage kv tile [kv0,kv0+64): K 16 chunks (4 rows x 256B), V 16 chunks
  // (8 rows x 128B); 8+8 per wave.  Source slot pre-swizzled (rule #21).
  auto stage = [&](int kv0, int buf) {
#pragma unroll
    for (int t = 0; t < 8; ++t) {
      const int ii = wave * 8 + t;
      const int kvr = ii * 4 + (lane >> 4);
      async_copy16(Kb + (size_t)(kv0 + kvr) * 256 + 8 * ((lane & 15) ^ (kvr & 15)),
                   (char*)Ks[buf] + ii * 1024);
    }
#pragma unroll
    for (int t = 0; t < 8; ++t) {
      const int jj = wave * 8 + t;
      const int dr = jj * 8 + (lane >> 3);
      async_copy16(Vb + (size_t)dr * 2048 + kv0 + 8 * ((lane & 7) ^ (dr & 7)),
                   (char*)Vs[buf] + jj * 1024);
    }
  };

  // normalize + write 32 q-rows (this wave) of one head
  auto epilogue = [&](int q0) {
    const float lt = lacc + __shfl_xor(lacc, 32, 64);
    const float linv = 1.0f / lt;          // lane l: linv for q-row l31
    float li[16];
#pragma unroll
    for (int r = 0; r < 16; ++r)
      li[r] = __shfl(linv, (r & 3) + 8 * (r >> 2) + 4 * hi, 64);
#pragma unroll
    for (int nt = 0; nt < 4; ++nt)
#pragma unroll
      for (int r = 0; r < 16; ++r) {
        const int qr = (r & 3) + 8 * (r >> 2) + 4 * hi;
        const int s = q0 + wrow + qr;
        O[((size_t)(b * 2048 + s)) * 2048 + h * 128 + nt * 32 + l31] =
            (bf16)(oacc[nt][r] * li[r]);
      }
  };

  int q0 = y * 64;       // part 0: light tile
  load_q(q0);
  reset_acc();
  stage(0, 0);

  for (int jt = 0; jt < 33; ++jt) {
    const int kv0 = (jt < nkvA ? jt : jt - nkvA) * 64;
    const int buf = jt & 1;
    __syncthreads();  // own DMA drained (buf visible); prior iter's reads done
    if (jt + 1 < 33) {
      const int njt = jt + 1;
      stage((njt < nkvA ? njt : njt - nkvA) * 64, buf ^ 1);
    }

    if (kv0 <= q0 + wrow + 31) {  // wave-uniform skip of fully-masked tiles
      sacc[0] = vz16;
      sacc[1] = vz16;
      // S^T[kv][q] = K.Q^T: A=K-frag [m=kv=32mt+l31][k=16ks+8hi+j],
      // slot = (2ks+hi)^l15 (swizzle uses kv&15 = l15)
      __builtin_amdgcn_s_setprio(1);
#pragma unroll
      for (int ks = 0; ks < 8; ++ks) {
        const int sl = ((2 * ks + hi) ^ l15) << 4;
        bf16x8 ka0 = *(const bf16x8*)((const char*)Ks[buf] + l31 * 256 + sl);
        bf16x8 ka1 = *(const bf16x8*)((const char*)Ks[buf] + (32 + l31) * 256 + sl);
        sacc[0] = MFMA32(ka0, qb[ks], sacc[0]);
        sacc[1] = MFMA32(ka1, qb[ks], sacc[1]);
      }
      __builtin_amdgcn_s_setprio(0);

      // P = exp(S); mask iff tile max-key can exceed wave MIN row.
      const int qg = q0 + wrow + l31;
      float p[32];
      if (kv0 + 63 > q0 + wrow) {
#pragma unroll
        for (int mt = 0; mt < 2; ++mt)
#pragma unroll
          for (int r = 0; r < 16; ++r) {
            const int kg = kv0 + mt * 32 + (r & 3) + 8 * (r >> 2) + 4 * hi;
            p[mt * 16 + r] = (kg > qg) ? 0.0f : __expf(sacc[mt][r]);
          }
      } else {
#pragma unroll
        for (int mt = 0; mt < 2; ++mt)
#pragma unroll
          for (int r = 0; r < 16; ++r)
            p[mt * 16 + r] = __expf(sacc[mt][r]);
      }
#pragma unroll
      for (int i = 0; i < 32; ++i) lacc += p[i];

      // P C-layout -> A-frags: per mt, 8 cvt_pk + 4 permlane32_swap.
      // A-frag ks dwords: d0=(8hi+0,1) d1=(8hi+2,3) d2=(8hi+4,5) d3=(8hi+6,7)
      bf16x8 pa[4];
#pragma unroll
      for (int mt = 0; mt < 2; ++mt) {
        const int o = mt * 16;
        unsigned a0 = cvtpk(p[o + 0], p[o + 1]);
        unsigned b0 = cvtpk(p[o + 4], p[o + 5]);
        pl32swap(a0, b0, hi);                  // a0=d0, b0=d2  (ksl=0)
        unsigned a1 = cvtpk(p[o + 2], p[o + 3]);
        unsigned b1 = cvtpk(p[o + 6], p[o + 7]);
        pl32swap(a1, b1, hi);                  // a1=d1, b1=d3
        pa[mt * 2 + 0] = frag4(a0, a1, b0, b1);
        unsigned a2 = cvtpk(p[o + 8], p[o + 9]);
        unsigned b2 = cvtpk(p[o + 12], p[o + 13]);
        pl32swap(a2, b2, hi);                  // ksl=1
        unsigned a3 = cvtpk(p[o + 10], p[o + 11]);
        unsigned b3 = cvtpk(p[o + 14], p[o + 15]);
        pl32swap(a3, b3, hi);
        pa[mt * 2 + 1] = frag4(a2, a3, b2, b3);
      }

      // O += P V: A=pa[ks], B=V-frag [k=kv=16ks+8hi+j][n=d=32nt+l31],
      // slot = (2ks+hi)^(d&7) = (2ks+hi)^l7
      __builtin_amdgcn_s_setprio(1);
#pragma unroll
      for (int ks = 0; ks < 4; ++ks) {
        const int sl = ((2 * ks + hi) ^ l7) << 4;
#pragma unroll
        for (int nt = 0; nt < 4; ++nt) {
          bf16x8 vb = *(const bf16x8*)((const char*)Vs[buf] + (nt * 32 + l31) * 128 + sl);
          oacc[nt] = MFMA32(pa[ks], vb, oacc[nt]);
        }
      }
      __builtin_amdgcn_s_setprio(0);
    }

    if (jt == nkvA - 1) {  // part boundary (block-uniform): flush light tile
      epilogue(q0);
      reset_acc();
      q0 = (31 - y) * 64;  // part 1: heavy tile
      load_q(q0);
    }
  }
  epilogue(q0);
}

// ---------------------------------------------------------------------------
extern "C" void kernel_launch(void* const* d_in, const int* in_sizes, int n_in,
                              void* d_out, int out_size, void* d_ws, size_t ws_size,
                              hipStream_t stream) {
  const float* hs     = (const float*)d_in[0];  // [2,2048,2048] fp32
  const float* w_q    = (const float*)d_in[1];  // [2048,2048]   fp32
  const float* w_kv   = (const float*)d_in[2];  // [256,2048]    fp32
  const float* w_proj = (const float*)d_in[3];  // [2048,2048]   fp32
  const float* b_proj = (const float*)d_in[4];  // [2048]        fp32
  float* out = (float*)d_out;                   // [2,2048,2048] FP32 (33.6 MB)
  bf16* Qbuf  = (bf16*)d_out;                   // bf16 Q scratch, lower 16.78 MB
  bf16* hs_bf = (bf16*)((char*)d_out + 16777216);  // bf16 hs, upper 16.78 MB

  char* ws = (char*)d_ws;                          // ws use: 35 MB
  bf16* Ckv      = (bf16*)(ws);                    //  2 MB: [4096,256]
  bf16* VT       = (bf16*)(ws + 2097152);          //  1 MB: [2,128,2048]
  bf16* AO       = (bf16*)(ws + 3145728);          // 16.78 MB: [4096,2048]
  bf16* wqkv_bf  = (bf16*)(ws + 19922944);         //  9.4 MB: [2304,2048]
  bf16* wproj_bf = (bf16*)(ws + 29360128);         //  8.4 MB: [2048,2048]

  convert_bf16<<<dim3(8448), dim3(256), 0, stream>>>(hs, w_q, w_kv, w_proj,
                                                     hs_bf, wqkv_bf, wproj_bf);
  gemm_qkv<<<dim3(18, 32), dim3(256), 0, stream>>>(hs_bf, wqkv_bf, Qbuf, Ckv);
  rotary_kernel<<<dim3(4096), dim3(256), 0, stream>>>(Qbuf, Ckv, VT);
  flash_attn<<<dim3(32, 16), dim3(128), 0, stream>>>(Qbuf, Ckv, VT, AO);
  gemm_proj<<<dim3(16, 32), dim3(256), 0, stream>>>(AO, wproj_bf, b_proj, out);
}

// Round 6
// 276.334 us; speedup vs baseline: 1.0423x; 1.0423x over previous
//
#include <hip/hip_runtime.h>
#include <math.h>

typedef __bf16 bf16;
typedef __bf16 bf16x8 __attribute__((ext_vector_type(8)));
typedef float f32x4 __attribute__((ext_vector_type(4)));
typedef float f32x16 __attribute__((ext_vector_type(16)));

#define MFMA16(a, b, c) __builtin_amdgcn_mfma_f32_16x16x32_bf16((a), (b), (c), 0, 0, 0)
#define MFMA32(a, b, c) __builtin_amdgcn_mfma_f32_32x32x16_bf16((a), (b), (c), 0, 0, 0)

// NaN-laundering clamp (IEEE min/max drop NaN); inert on good data.
__device__ __forceinline__ float clampf(float v, float lo, float hi) {
  return fminf(fmaxf(v, lo), hi);
}

// Async global->LDS DMA, 16B per lane; lane i's 16B lands at base + i*16.
__device__ __forceinline__ void async_copy16(const void* g, void* l) {
  __builtin_amdgcn_global_load_lds(
      (__attribute__((address_space(1))) void*)g,
      (__attribute__((address_space(3))) void*)l,
      16, 0, 0);
}

// v_cvt_pk_bf16_f32: dword = {lo: bf16(a), hi: bf16(b)}
__device__ __forceinline__ unsigned cvtpk(float a, float b) {
  unsigned r;
  asm("v_cvt_pk_bf16_f32 %0, %1, %2" : "=v"(r) : "v"(a), "v"(b));
  return r;
}

// permlane32_swap: (a,b) -> (concat(a.lo32, b.lo32), concat(a.hi32, b.hi32))
__device__ __forceinline__ void pl32swap(unsigned& a, unsigned& b, int hi) {
#if __has_builtin(__builtin_amdgcn_permlane32_swap)
  auto r = __builtin_amdgcn_permlane32_swap(a, b, false, false);
  a = r[0];
  b = r[1];
#else
  unsigned ax = (unsigned)__shfl_xor((int)a, 32, 64);
  unsigned bx = (unsigned)__shfl_xor((int)b, 32, 64);
  unsigned o0 = hi ? bx : a;
  unsigned o1 = hi ? b : ax;
  a = o0; b = o1;
#endif
}

__device__ __forceinline__ bf16x8 frag4(unsigned d0, unsigned d1, unsigned d2, unsigned d3) {
  union { unsigned u[4]; bf16x8 v; } t;
  t.u[0] = d0; t.u[1] = d1; t.u[2] = d2; t.u[3] = d3;
  return t.v;
}

// ---------------------------------------------------------------------------
// B=2, S=2048, D_MODEL=2048, H=16, HEAD=128.  R5 post-mortem: 128-thr blocks
// + 64KB LDS -> 2 blocks/CU -> 1 wave/SIMD; all latencies exposed (93us,
// occ 10.7%).  R6: SAME 32x32 swapped-QK^T in-reg-P inner loop, but 4-wave
// blocks (256 thr, 128-row tile), unpaired contiguous kv loop.  Grid
// (32,16)=512 blocks, all resident (2/CU) -> 2 waves/SIMD.  Balance via
// DISPATCH-ORDER pairing: order L<8 -> y=L (light), L>=8 -> y=23-L (heavy);
// breadth-first fill co-locates block c with c+256 -> per-CU iter sum = 34.
// ---------------------------------------------------------------------------

// Elementwise fp32->bf16, 8 elems/thread.  Region boundaries in vec8 units:
// hs 1048576 | w_q 524288 | w_kv 65536 | w_proj 524288  (total 2162688).
__global__ void convert_bf16(const float* __restrict__ hs,
                             const float* __restrict__ wq,
                             const float* __restrict__ wkv,
                             const float* __restrict__ wproj,
                             bf16* __restrict__ hs_bf,
                             bf16* __restrict__ wqkv_bf,
                             bf16* __restrict__ wproj_bf) {
  const long long v = (long long)blockIdx.x * blockDim.x + threadIdx.x;
  const float* src;
  bf16* dst;
  long long off;
  if (v < 1048576) { src = hs; dst = hs_bf; off = v; }
  else if (v < 1572864) { src = wq; dst = wqkv_bf; off = v - 1048576; }
  else if (v < 1638400) { src = wkv; dst = wqkv_bf + 4194304; off = v - 1572864; }
  else { src = wproj; dst = wproj_bf; off = v - 1638400; }
  const f32x4* p = (const f32x4*)(src + off * 8);
  f32x4 f0 = p[0], f1 = p[1];
  bf16x8 r;
#pragma unroll
  for (int i = 0; i < 4; ++i) { r[i] = (bf16)f0[i]; r[i + 4] = (bf16)f1[i]; }
  *(bf16x8*)(dst + off * 8) = r;
}

// GEMM1 (m97-style): Qbuf = hs_bf @ wqkv^T cols 0..2047 (bx<16),
// Ckv = cols 2048..2303 (bx 16..17).  128x128 tile, BK=32, DMA staging.
// Bijective XCD-chunk swizzle on the linearized grid (576 = 72*8).
__global__ __launch_bounds__(256, 2)
void gemm_qkv(const bf16* __restrict__ A, const bf16* __restrict__ Bw,
              bf16* __restrict__ Cq, bf16* __restrict__ Ckv) {
  const int K = 2048;
  __shared__ bf16 As[128 * 32];
  __shared__ bf16 Bs[128 * 32];
  const int tid = threadIdx.x;
  const int wave = tid >> 6, lane = tid & 63;
  const int quad = lane >> 4, l15 = lane & 15;
  const int r4 = lane >> 2, c4 = lane & 3;
  const int wm = wave >> 1, wn = wave & 1;
  const int orig = blockIdx.x + 18 * blockIdx.y;
  const int wgid = (orig & 7) * 72 + (orig >> 3);
  const int bx = wgid % 18;
  const int bm = (wgid / 18) * 128;
  const bf16* Bp = Bw + (size_t)bx * 128 * K;

  const f32x4 vzero = {0.f, 0.f, 0.f, 0.f};
  f32x4 acc[4][4];
#pragma unroll
  for (int i = 0; i < 4; ++i)
#pragma unroll
    for (int j = 0; j < 4; ++j) acc[i][j] = vzero;

  for (int kt = 0; kt < K; kt += 32) {
    __syncthreads();
#pragma unroll
    for (int q = 0; q < 2; ++q) {
      const int chunk = wave * 2 + q;
      const int row = chunk * 16 + r4;
      async_copy16(A + (size_t)(bm + row) * K + kt + c4 * 8, (char*)As + chunk * 1024);
      async_copy16(Bp + (size_t)row * K + kt + c4 * 8, (char*)Bs + chunk * 1024);
    }
    __syncthreads();
    bf16x8 af[4], bfr[4];
#pragma unroll
    for (int i = 0; i < 4; ++i)
      af[i] = *(const bf16x8*)((const char*)As + (wm * 64 + i * 16 + l15) * 64 + quad * 16);
#pragma unroll
    for (int i = 0; i < 4; ++i)
      bfr[i] = *(const bf16x8*)((const char*)Bs + (wn * 64 + i * 16 + l15) * 64 + quad * 16);
#pragma unroll
    for (int mi = 0; mi < 4; ++mi)
#pragma unroll
      for (int ni = 0; ni < 4; ++ni)
        acc[mi][ni] = MFMA16(af[mi], bfr[ni], acc[mi][ni]);
  }

  bf16* Cp;
  int ldc, cn;
  if (bx < 16) { Cp = Cq; ldc = 2048; cn = bx * 128; }
  else { Cp = Ckv; ldc = 256; cn = (bx - 16) * 128; }
#pragma unroll
  for (int mi = 0; mi < 4; ++mi)
#pragma unroll
    for (int ni = 0; ni < 4; ++ni) {
      const int col = cn + wn * 64 + ni * 16 + l15;
#pragma unroll
      for (int r = 0; r < 4; ++r) {
        const int row = bm + wm * 64 + mi * 16 + quad * 4 + r;
        Cp[(size_t)row * ldc + col] = (bf16)clampf(acc[mi][ni][r], -1000.f, 1000.f);
      }
    }
}

// GEMM2 (m97-style): d_out(FP32) = AO(bf16) @ wproj_bf^T + b_proj(fp32).
// Bijective XCD-chunk swizzle (512 = 64*8).
__global__ __launch_bounds__(256, 2)
void gemm_proj(const bf16* __restrict__ A, const bf16* __restrict__ Bw,
               const float* __restrict__ bias, float* __restrict__ C) {
  const int K = 2048;
  __shared__ bf16 As[128 * 32];
  __shared__ bf16 Bs[128 * 32];
  const int tid = threadIdx.x;
  const int wave = tid >> 6, lane = tid & 63;
  const int quad = lane >> 4, l15 = lane & 15;
  const int r4 = lane >> 2, c4 = lane & 3;
  const int wm = wave >> 1, wn = wave & 1;
  const int orig = blockIdx.x + 16 * blockIdx.y;
  const int wgid = (orig & 7) * 64 + (orig >> 3);
  const int bn = (wgid % 16) * 128;
  const int bm = (wgid / 16) * 128;
  const bf16* Bp = Bw + (size_t)bn * K;

  const f32x4 vzero = {0.f, 0.f, 0.f, 0.f};
  f32x4 acc[4][4];
#pragma unroll
  for (int i = 0; i < 4; ++i)
#pragma unroll
    for (int j = 0; j < 4; ++j) acc[i][j] = vzero;

  for (int kt = 0; kt < K; kt += 32) {
    __syncthreads();
#pragma unroll
    for (int q = 0; q < 2; ++q) {
      const int chunk = wave * 2 + q;
      const int row = chunk * 16 + r4;
      async_copy16(A + (size_t)(bm + row) * K + kt + c4 * 8, (char*)As + chunk * 1024);
      async_copy16(Bp + (size_t)row * K + kt + c4 * 8, (char*)Bs + chunk * 1024);
    }
    __syncthreads();
    bf16x8 af[4], bfr[4];
#pragma unroll
    for (int i = 0; i < 4; ++i)
      af[i] = *(const bf16x8*)((const char*)As + (wm * 64 + i * 16 + l15) * 64 + quad * 16);
#pragma unroll
    for (int i = 0; i < 4; ++i)
      bfr[i] = *(const bf16x8*)((const char*)Bs + (wn * 64 + i * 16 + l15) * 64 + quad * 16);
#pragma unroll
    for (int mi = 0; mi < 4; ++mi)
#pragma unroll
      for (int ni = 0; ni < 4; ++ni)
        acc[mi][ni] = MFMA16(af[mi], bfr[ni], acc[mi][ni]);
  }

#pragma unroll
  for (int mi = 0; mi < 4; ++mi)
#pragma unroll
    for (int ni = 0; ni < 4; ++ni) {
      const int col = bn + wn * 64 + ni * 16 + l15;
      const float bv = bias[col];
#pragma unroll
      for (int r = 0; r < 4; ++r) {
        const int row = bm + wm * 64 + mi * 16 + quad * 4 + r;
        C[(size_t)row * 2048 + col] = clampf(acc[mi][ni][r] + bv, -1000.f, 1000.f);
      }
    }
}

// Rotary xpos + head-dim scale. Q in place in Qbuf(bf16) [row, h*128+d].
// K in place in Ckv cols 0..127. V (Ckv cols 128..255) -> VT [b,d,s].
__global__ void rotary_kernel(bf16* __restrict__ Cq, bf16* __restrict__ Ckv,
                              bf16* __restrict__ VT) {
  const int row = blockIdx.x;            // b*2048 + s
  const int b = row >> 11, s = row & 2047;
  const int t = threadIdx.x;
  const float power = (float)(s - 1024) * (1.0f / 512.0f);
  const float scale_w = 0.08838834764831845f;  // 128^-0.5
  const float k_if = 0.2076205059304679f;      // log2(10000)/64

  const int h = t >> 4;
  const int j0 = (t & 15) * 4;
  const size_t qbase = (size_t)row * 2048 + (size_t)h * 128;
#pragma unroll
  for (int u = 0; u < 4; ++u) {
    const int j = j0 + u;
    const float pos = (float)s * exp2f(-k_if * (float)j);
    const float c = cosf(pos), sn = sinf(pos);
    const float sb = ((float)(2 * j) + 51.2f) * (1.0f / 179.2f);
    const float xs = exp2f(power * log2f(sb));
    const float f = xs * scale_w;
    const float q1 = (float)Cq[qbase + j];
    const float q2 = (float)Cq[qbase + j + 64];
    Cq[qbase + j]      = (bf16)((q1 * c - q2 * sn) * f);
    Cq[qbase + j + 64] = (bf16)((q2 * c + q1 * sn) * f);
  }

  if (t < 64) {  // K in place, xpos scale inverted
    const int j = t;
    const float pos = (float)s * exp2f(-k_if * (float)j);
    const float c = cosf(pos), sn = sinf(pos);
    const float sb = ((float)(2 * j) + 51.2f) * (1.0f / 179.2f);
    const float xs = exp2f(power * log2f(sb));
    const float f = scale_w / xs;
    const size_t kvb = (size_t)row * 256;
    const float k1 = (float)Ckv[kvb + j];
    const float k2 = (float)Ckv[kvb + j + 64];
    Ckv[kvb + j]      = (bf16)((k1 * c - k2 * sn) * f);
    Ckv[kvb + j + 64] = (bf16)((k2 * c + k1 * sn) * f);
  } else if (t < 128) {  // V -> VT [b,d,s]
    const int d = (t - 64) * 2;
    const size_t kvb = (size_t)row * 256 + 128;
    VT[((size_t)b * 128 + d) * 2048 + s]     = Ckv[kvb + d];
    VT[((size_t)b * 128 + d + 1) * 2048 + s] = Ckv[kvb + d + 1];
  }
}

// Causal flash attention, MQA.  grid = (32 bh, 16 order-slots); 256 threads
// = 4 waves x 32 q-rows (128-row tile).  Order L<8 -> y=L (light), L>=8 ->
// y=23-L (heavy): co-resident blocks c & c+256 sum to 34 kv-iters.
// 32x32x16 MFMA, swapped QK^T (mfma(K,Q)): lane owns q-row q0+wrow+l31.
// P -> A-frags via cvt_pk + permlane32_swap (no LDS).  Row-sum l scalar.
// Ks [kv][128d] slot^=(kv&15); Vs [d][64kv] slot^=(d&7) (both-sides swz).
__global__ __launch_bounds__(256, 2)
void flash_attn(const bf16* __restrict__ Qp, const bf16* __restrict__ Kkv,
                const bf16* __restrict__ VT, bf16* __restrict__ O) {
  __shared__ bf16 Ks[2][64 * 128];   // 32 KB: [buf][kv][d], 256B rows, 16 slots
  __shared__ bf16 Vs[2][128 * 64];   // 32 KB: [buf][d][kv], 128B rows, 8 slots

  const int tid = threadIdx.x;
  const int wave = tid >> 6, lane = tid & 63;
  const int hi = lane >> 5, l31 = lane & 31, l15 = lane & 15, l7 = lane & 7;
  const int bh = blockIdx.x, b = bh >> 4, h = bh & 15;
  const int L = blockIdx.y;
  const int y = (L < 8) ? L : 23 - L;    // tile index 0..15 (128-row tiles)
  const int nkv = 2 * y + 2;             // kv-iters covering [0,(y+1)*128)
  const int q0 = y * 128;
  const int wrow = wave * 32;

  const bf16* Kb = Kkv + (size_t)b * 2048 * 256;
  const bf16* Vb = VT + (size_t)b * 128 * 2048;

  f32x16 sacc[2];
  f32x16 oacc[4];
  bf16x8 qb[8];
  float lacc = 0.f;
  const f32x16 vz16 = {0.f, 0.f, 0.f, 0.f, 0.f, 0.f, 0.f, 0.f,
                       0.f, 0.f, 0.f, 0.f, 0.f, 0.f, 0.f, 0.f};
#pragma unroll
  for (int nt = 0; nt < 4; ++nt) oacc[nt] = vz16;

  // Q B-fragments: B[n=q=l31][k=d_local=8hi+j], d = 16ks+8hi+j
#pragma unroll
  for (int ks = 0; ks < 8; ++ks)
    qb[ks] = *(const bf16x8*)(Qp + ((size_t)(b * 2048 + q0 + wrow + l31)) * 2048 +
                              h * 128 + ks * 16 + hi * 8);

  // stage kv tile [kv0,kv0+64): K 16 chunks (4 rows x 256B), V 16 chunks
  // (8 rows x 128B); 4+4 per wave.  Source slot pre-swizzled (rule #21).
  auto stage = [&](int kv0, int buf) {
#pragma unroll
    for (int t = 0; t < 4; ++t) {
      const int ii = wave * 4 + t;
      const int kvr = ii * 4 + (lane >> 4);
      async_copy16(Kb + (size_t)(kv0 + kvr) * 256 + 8 * ((lane & 15) ^ (kvr & 15)),
                   (char*)Ks[buf] + ii * 1024);
    }
#pragma unroll
    for (int t = 0; t < 4; ++t) {
      const int jj = wave * 4 + t;
      const int dr = jj * 8 + (lane >> 3);
      async_copy16(Vb + (size_t)dr * 2048 + kv0 + 8 * ((lane & 7) ^ (dr & 7)),
                   (char*)Vs[buf] + jj * 1024);
    }
  };

  stage(0, 0);

  for (int jt = 0; jt < nkv; ++jt) {
    const int kv0 = jt * 64;
    const int buf = jt & 1;
    __syncthreads();  // own DMA drained (buf visible); prior iter's reads done
    if (jt + 1 < nkv) stage(kv0 + 64, buf ^ 1);

    if (kv0 <= q0 + wrow + 31) {  // wave-uniform skip of fully-masked tiles
      sacc[0] = vz16;
      sacc[1] = vz16;
      // S^T[kv][q] = K.Q^T: A=K-frag [m=kv=32mt+l31][k=16ks+8hi+j],
      // slot = (2ks+hi)^l15 (swizzle uses kv&15 = l15)
      __builtin_amdgcn_s_setprio(1);
#pragma unroll
      for (int ks = 0; ks < 8; ++ks) {
        const int sl = ((2 * ks + hi) ^ l15) << 4;
        bf16x8 ka0 = *(const bf16x8*)((const char*)Ks[buf] + l31 * 256 + sl);
        bf16x8 ka1 = *(const bf16x8*)((const char*)Ks[buf] + (32 + l31) * 256 + sl);
        sacc[0] = MFMA32(ka0, qb[ks], sacc[0]);
        sacc[1] = MFMA32(ka1, qb[ks], sacc[1]);
      }
      __builtin_amdgcn_s_setprio(0);

      // P = exp(S); mask iff tile max-key can exceed wave MIN row.
      const int qg = q0 + wrow + l31;
      float p[32];
      if (kv0 + 63 > q0 + wrow) {
#pragma unroll
        for (int mt = 0; mt < 2; ++mt)
#pragma unroll
          for (int r = 0; r < 16; ++r) {
            const int kg = kv0 + mt * 32 + (r & 3) + 8 * (r >> 2) + 4 * hi;
            p[mt * 16 + r] = (kg > qg) ? 0.0f : __expf(sacc[mt][r]);
          }
      } else {
#pragma unroll
        for (int mt = 0; mt < 2; ++mt)
#pragma unroll
          for (int r = 0; r < 16; ++r)
            p[mt * 16 + r] = __expf(sacc[mt][r]);
      }
#pragma unroll
      for (int i = 0; i < 32; ++i) lacc += p[i];

      // P C-layout -> A-frags: per mt, 8 cvt_pk + 4 permlane32_swap.
      // A-frag ks dwords: d0=(8hi+0,1) d1=(8hi+2,3) d2=(8hi+4,5) d3=(8hi+6,7)
      bf16x8 pa[4];
#pragma unroll
      for (int mt = 0; mt < 2; ++mt) {
        const int o = mt * 16;
        unsigned a0 = cvtpk(p[o + 0], p[o + 1]);
        unsigned b0 = cvtpk(p[o + 4], p[o + 5]);
        pl32swap(a0, b0, hi);                  // a0=d0, b0=d2  (ksl=0)
        unsigned a1 = cvtpk(p[o + 2], p[o + 3]);
        unsigned b1 = cvtpk(p[o + 6], p[o + 7]);
        pl32swap(a1, b1, hi);                  // a1=d1, b1=d3
        pa[mt * 2 + 0] = frag4(a0, a1, b0, b1);
        unsigned a2 = cvtpk(p[o + 8], p[o + 9]);
        unsigned b2 = cvtpk(p[o + 12], p[o + 13]);
        pl32swap(a2, b2, hi);                  // ksl=1
        unsigned a3 = cvtpk(p[o + 10], p[o + 11]);
        unsigned b3 = cvtpk(p[o + 14], p[o + 15]);
        pl32swap(a3, b3, hi);
        pa[mt * 2 + 1] = frag4(a2, a3, b2, b3);
      }

      // O += P V: A=pa[ks], B=V-frag [k=kv=16ks+8hi+j][n=d=32nt+l31],
      // slot = (2ks+hi)^(d&7) = (2ks+hi)^l7
      __builtin_amdgcn_s_setprio(1);
#pragma unroll
      for (int ks = 0; ks < 4; ++ks) {
        const int sl = ((2 * ks + hi) ^ l7) << 4;
#pragma unroll
        for (int nt = 0; nt < 4; ++nt) {
          bf16x8 vb = *(const bf16x8*)((const char*)Vs[buf] + (nt * 32 + l31) * 128 + sl);
          oacc[nt] = MFMA32(pa[ks], vb, oacc[nt]);
        }
      }
      __builtin_amdgcn_s_setprio(0);
    }
  }

  // normalize + write 32 q-rows (this wave) of one head
  {
    const float lt = lacc + __shfl_xor(lacc, 32, 64);
    const float linv = 1.0f / lt;          // lane l: linv for q-row l31
    float li[16];
#pragma unroll
    for (int r = 0; r < 16; ++r)
      li[r] = __shfl(linv, (r & 3) + 8 * (r >> 2) + 4 * hi, 64);
#pragma unroll
    for (int nt = 0; nt < 4; ++nt)
#pragma unroll
      for (int r = 0; r < 16; ++r) {
        const int qr = (r & 3) + 8 * (r >> 2) + 4 * hi;
        const int s = q0 + wrow + qr;
        O[((size_t)(b * 2048 + s)) * 2048 + h * 128 + nt * 32 + l31] =
            (bf16)(oacc[nt][r] * li[r]);
      }
  }
}

// ---------------------------------------------------------------------------
extern "C" void kernel_launch(void* const* d_in, const int* in_sizes, int n_in,
                              void* d_out, int out_size, void* d_ws, size_t ws_size,
                              hipStream_t stream) {
  const float* hs     = (const float*)d_in[0];  // [2,2048,2048] fp32
  const float* w_q    = (const float*)d_in[1];  // [2048,2048]   fp32
  const float* w_kv   = (const float*)d_in[2];  // [256,2048]    fp32
  const float* w_proj = (const float*)d_in[3];  // [2048,2048]   fp32
  const float* b_proj = (const float*)d_in[4];  // [2048]        fp32
  float* out = (float*)d_out;                   // [2,2048,2048] FP32 (33.6 MB)
  bf16* Qbuf  = (bf16*)d_out;                   // bf16 Q scratch, lower 16.78 MB
  bf16* hs_bf = (bf16*)((char*)d_out + 16777216);  // bf16 hs, upper 16.78 MB

  char* ws = (char*)d_ws;                          // ws use: 35 MB
  bf16* Ckv      = (bf16*)(ws);                    //  2 MB: [4096,256]
  bf16* VT       = (bf16*)(ws + 2097152);          //  1 MB: [2,128,2048]
  bf16* AO       = (bf16*)(ws + 3145728);          // 16.78 MB: [4096,2048]
  bf16* wqkv_bf  = (bf16*)(ws + 19922944);         //  9.4 MB: [2304,2048]
  bf16* wproj_bf = (bf16*)(ws + 29360128);         //  8.4 MB: [2048,2048]

  convert_bf16<<<dim3(8448), dim3(256), 0, stream>>>(hs, w_q, w_kv, w_proj,
                                                     hs_bf, wqkv_bf, wproj_bf);
  gemm_qkv<<<dim3(18, 32), dim3(256), 0, stream>>>(hs_bf, wqkv_bf, Qbuf, Ckv);
  rotary_kernel<<<dim3(4096), dim3(256), 0, stream>>>(Qbuf, Ckv, VT);
  flash_attn<<<dim3(32, 16), dim3(256), 0, stream>>>(Qbuf, Ckv, VT, AO);
  gemm_proj<<<dim3(16, 32), dim3(256), 0, stream>>>(AO, wproj_bf, b_proj, out);
}